// Round 1
// baseline (626.143 us; speedup 1.0000x reference)
//
#include <hip/hip_runtime.h>

// Problem constants (B=4, S=4096, D=1024, BASE_K=256, MAX_K=512)
#define SDIM 4096
#define DDIM 1024
#define NROWS 16384
#define KOUT 512

__device__ __forceinline__ unsigned f2key(float f) {
    unsigned u = __float_as_uint(f);
    // monotonic transform: larger key <=> larger float (bijective)
    return (u & 0x80000000u) ? ~u : (u | 0x80000000u);
}
__device__ __forceinline__ float key2f(unsigned k) {
    unsigned u = (k & 0x80000000u) ? (k ^ 0x80000000u) : ~k;
    return __uint_as_float(u);
}

// ---------------- gate kernel: k_per_query ----------------
// one wave per row, 4 waves per block
__global__ __launch_bounds__(256) void gate_kernel(
    const float* __restrict__ Q, const float* __restrict__ W,
    const float* __restrict__ bias, float* __restrict__ outk) {
    const int wave = threadIdx.x >> 6;
    const int lane = threadIdx.x & 63;
    const int row = blockIdx.x * 4 + wave;
    if (row >= NROWS) return;
    const float4* q  = (const float4*)(Q + (size_t)row * DDIM);
    const float4* w4 = (const float4*)W;
    float acc = 0.f;
#pragma unroll
    for (int i = 0; i < DDIM / 4 / 64; ++i) {
        float4 a = q[lane + i * 64];
        float4 b = w4[lane + i * 64];
        acc += a.x * b.x + a.y * b.y + a.z * b.z + a.w * b.w;
    }
#pragma unroll
    for (int off = 32; off >= 1; off >>= 1)
        acc += __shfl_down(acc, off, 64);
    if (lane == 0) {
        float x   = acc + bias[0];
        float imp = 1.0f / (1.0f + expf(-x));
        int   k   = (int)(256.0f + 256.0f * imp);  // trunc toward zero
        outk[row] = (float)k;
    }
}

// ---------------- top-k kernel: one block (256 thr) per row ----------------
__global__ __launch_bounds__(256) void topk_kernel(
    const float* __restrict__ scores, float* __restrict__ out) {
    __shared__ unsigned keys[SDIM];   // 16 KB
    __shared__ unsigned hist[256];    // 1 KB
    __shared__ unsigned sel[KOUT];    // 2 KB
    __shared__ unsigned s_bucket, s_above, s_cnt;

    const int tid = threadIdx.x;
    const size_t row = blockIdx.x;
    const float4* src = (const float4*)(scores + row * (size_t)SDIM);

    // load + transform to monotonic uint keys
#pragma unroll
    for (int i = 0; i < 4; ++i) {
        int idx = tid + i * 256;            // [0,1024)
        float4 v = src[idx];
        keys[idx * 4 + 0] = f2key(v.x);
        keys[idx * 4 + 1] = f2key(v.y);
        keys[idx * 4 + 2] = f2key(v.z);
        keys[idx * 4 + 3] = f2key(v.w);
    }
    if (tid == 0) s_cnt = 0;

    // exact radix select: find key T of the 512th largest element
    unsigned prefix = 0;
    unsigned K = KOUT;
#pragma unroll
    for (int level = 3; level >= 0; --level) {
        const int shift = level * 8;
        const unsigned maskHi = (level == 3) ? 0u : (0xFFFFFFFFu << (shift + 8));
        hist[tid] = 0;
        __syncthreads();
#pragma unroll
        for (int i = 0; i < SDIM / 256; ++i) {
            unsigned key = keys[tid + i * 256];
            if ((key & maskHi) == prefix)
                atomicAdd(&hist[(key >> shift) & 0xFFu], 1u);
        }
        __syncthreads();
        // inclusive suffix sum: hist[t] = count(bucket >= t)
        for (int d = 1; d < 256; d <<= 1) {
            unsigned v = hist[tid];
            unsigned a = (tid + d < 256) ? hist[tid + d] : 0u;
            __syncthreads();
            hist[tid] = v + a;
            __syncthreads();
        }
        unsigned mine = hist[tid];
        unsigned nxt  = (tid < 255) ? hist[tid + 1] : 0u;
        if (mine >= K && nxt < K) { s_bucket = (unsigned)tid; s_above = nxt; }
        __syncthreads();
        prefix |= (s_bucket << shift);
        K -= s_above;
        __syncthreads();  // protect hist/s_bucket before next-level reuse
    }
    const unsigned T = prefix;  // exact key of the K-th largest

    // compact strictly-greater keys; ties all equal T exactly
#pragma unroll
    for (int i = 0; i < SDIM / 256; ++i) {
        unsigned key = keys[tid + i * 256];
        if (key > T) {
            unsigned p = atomicAdd(&s_cnt, 1u);
            sel[p] = key;  // p < 512 guaranteed by select
        }
    }
    __syncthreads();
    const unsigned m = s_cnt;  // == 512 - K_final
#pragma unroll
    for (int t = 0; t < 2; ++t) {
        int i = tid + t * 256;
        if ((unsigned)i >= m) sel[i] = T;
    }
    __syncthreads();

    // bitonic sort 512 keys, descending
    for (int k = 2; k <= KOUT; k <<= 1) {
        for (int j = k >> 1; j >= 1; j >>= 1) {
#pragma unroll
            for (int t = 0; t < 2; ++t) {
                int i = tid + t * 256;
                int ixj = i ^ j;
                if (ixj > i) {
                    unsigned a = sel[i], b = sel[ixj];
                    bool desc = ((i & k) == 0);
                    if (desc ? (a < b) : (a > b)) { sel[i] = b; sel[ixj] = a; }
                }
            }
            __syncthreads();
        }
    }

    float* dst = out + row * (size_t)KOUT;
#pragma unroll
    for (int t = 0; t < 2; ++t) {
        int i = tid + t * 256;
        dst[i] = key2f(sel[i]);
    }
}

extern "C" void kernel_launch(void* const* d_in, const int* in_sizes, int n_in,
                              void* d_out, int out_size, void* d_ws, size_t ws_size,
                              hipStream_t stream) {
    const float* Q      = (const float*)d_in[0];
    const float* scores = (const float*)d_in[1];
    const float* W      = (const float*)d_in[2];
    const float* b      = (const float*)d_in[3];
    float* out_topk = (float*)d_out;                       // [16384, 512]
    float* out_k    = (float*)d_out + (size_t)NROWS * KOUT; // [16384]

    topk_kernel<<<NROWS, 256, 0, stream>>>(scores, out_topk);
    gate_kernel<<<NROWS / 4, 256, 0, stream>>>(Q, W, b, out_k);
}

// Round 2
// 548.930 us; speedup vs baseline: 1.1407x; 1.1407x over previous
//
#include <hip/hip_runtime.h>

// Problem constants (B=4, S=4096, D=1024, BASE_K=256, MAX_K=512)
#define SDIM 4096
#define DDIM 1024
#define NROWS 16384
#define KOUT 512

__device__ __forceinline__ unsigned f2key(float f) {
    unsigned u = __float_as_uint(f);
    // monotonic bijection: larger key <=> larger float
    return (u & 0x80000000u) ? ~u : (u | 0x80000000u);
}
__device__ __forceinline__ float key2f(unsigned k) {
    unsigned u = (k & 0x80000000u) ? (k ^ 0x80000000u) : ~k;
    return __uint_as_float(u);
}

// One block (256 threads) per row. Fuses:
//  - gate: k_per_query = trunc(256 + 256*sigmoid(Q_row . W + b))
//  - top-512 of scores_row, sorted descending (exact, bit-exact copies)
__global__ __launch_bounds__(256) void fused_kernel(
    const float* __restrict__ scores, const float* __restrict__ Q,
    const float* __restrict__ W, const float* __restrict__ bias,
    float* __restrict__ out_topk, float* __restrict__ out_k) {

    __shared__ unsigned sel[KOUT];      // 2 KB: compaction + sort exchange
    __shared__ unsigned wsum[2][4];     // ping-pong cross-wave count combine
    __shared__ float    fsum[4];
    __shared__ unsigned s_cnt;

    const int tid  = threadIdx.x;
    const int row  = blockIdx.x;
    const int lane = tid & 63;
    const int wid  = tid >> 6;

    if (tid == 0) s_cnt = 0;

    // ---------------- gate (fused) ----------------
    {
        float4 qv = ((const float4*)(Q + (size_t)row * DDIM))[tid];  // 256*4 = 1024 = DDIM
        float4 wv = ((const float4*)W)[tid];
        float g = qv.x * wv.x + qv.y * wv.y + qv.z * wv.z + qv.w * wv.w;
#pragma unroll
        for (int off = 32; off; off >>= 1) g += __shfl_down(g, off, 64);
        if (lane == 0) fsum[wid] = g;
    }
    __syncthreads();
    if (tid == 0) {
        float x   = fsum[0] + fsum[1] + fsum[2] + fsum[3] + bias[0];
        float imp = 1.0f / (1.0f + expf(-x));
        out_k[row] = (float)(int)(256.0f + 256.0f * imp);
    }

    // ---------------- load row into registers as monotonic keys ----------------
    unsigned key[16];
    {
        const float4* src = (const float4*)(scores + (size_t)row * SDIM);
#pragma unroll
        for (int i = 0; i < 4; ++i) {
            float4 v = src[tid + i * 256];
            key[4 * i + 0] = f2key(v.x);
            key[4 * i + 1] = f2key(v.y);
            key[4 * i + 2] = f2key(v.z);
            key[4 * i + 3] = f2key(v.w);
        }
    }

    // ---------------- exact threshold via 32-step bitwise binary search ------
    // T = max u32 with count(key >= T) >= 512  (== the 512th-largest key)
    unsigned prefix = 0;
    for (int b = 31; b >= 0; --b) {
        const unsigned cand = prefix | (1u << b);
        unsigned cnt = 0;
#pragma unroll
        for (int i = 0; i < 16; ++i) cnt += (key[i] >= cand) ? 1u : 0u;
#pragma unroll
        for (int off = 32; off; off >>= 1) cnt += __shfl_down(cnt, off, 64);
        if (lane == 0) wsum[b & 1][wid] = cnt;
        __syncthreads();
        const unsigned* ws = wsum[b & 1];
        unsigned total = ws[0] + ws[1] + ws[2] + ws[3];
        if (total >= (unsigned)KOUT) prefix = cand;
        // no second barrier: next iter writes the other wsum slot (ping-pong)
    }
    const unsigned T = prefix;

    // ---------------- compact strictly-greater, pad ties with T --------------
#pragma unroll
    for (int i = 0; i < 16; ++i) {
        if (key[i] > T) {
            unsigned p = atomicAdd(&s_cnt, 1u);  // < 512 guaranteed
            sel[p] = key[i];
        }
    }
    __syncthreads();
    const unsigned m = s_cnt;  // count(key > T) <= 511
    if ((unsigned)tid >= m)        sel[tid]       = T;
    if ((unsigned)(tid + 256) >= m) sel[tid + 256] = T;
    __syncthreads();

    // ---------------- bitonic sort 512 descending (hybrid shfl/LDS) ----------
    unsigned x0 = sel[tid], x1 = sel[tid + 256];  // elements i0=tid, i1=tid+256

    auto shflpass = [&](int kk, int j) {
        unsigned p0 = __shfl_xor(x0, j, 64);
        unsigned p1 = __shfl_xor(x1, j, 64);
        bool l0 = (tid & j) == 0;                  // am I the lower index of the pair
        bool d0 = (tid & kk) == 0;                 // descending region for i0
        bool d1 = ((tid + 256) & kk) == 0;         // descending region for i1
        x0 = (l0 == d0) ? (x0 > p0 ? x0 : p0) : (x0 < p0 ? x0 : p0);
        x1 = (l0 == d1) ? (x1 > p1 ? x1 : p1) : (x1 < p1 ? x1 : p1);
    };
    auto ldspass = [&](int kk, int j) {            // j in {64,128}: cross-wave
        sel[tid] = x0; sel[tid + 256] = x1;
        __syncthreads();
        unsigned p0 = sel[tid ^ j];
        unsigned p1 = sel[(tid ^ j) + 256];
        bool l0 = (tid & j) == 0;
        bool d0 = (tid & kk) == 0;
        bool d1 = ((tid + 256) & kk) == 0;
        x0 = (l0 == d0) ? (x0 > p0 ? x0 : p0) : (x0 < p0 ? x0 : p0);
        x1 = (l0 == d1) ? (x1 > p1 ? x1 : p1) : (x1 < p1 ? x1 : p1);
        __syncthreads();
    };

    for (int kk = 2; kk <= 64; kk <<= 1)
        for (int j = kk >> 1; j >= 1; j >>= 1) shflpass(kk, j);
    // kk = 128
    ldspass(128, 64);
    for (int j = 32; j >= 1; j >>= 1) shflpass(128, j);
    // kk = 256
    ldspass(256, 128);
    ldspass(256, 64);
    for (int j = 32; j >= 1; j >>= 1) shflpass(256, j);
    // kk = 512: j=256 is the in-thread pair (i0=tid, i1=tid+256), desc for both
    {
        unsigned hi = x0 > x1 ? x0 : x1;
        unsigned lo = x0 > x1 ? x1 : x0;
        x0 = hi; x1 = lo;
    }
    ldspass(512, 128);
    ldspass(512, 64);
    for (int j = 32; j >= 1; j >>= 1) shflpass(512, j);

    // ---------------- store ----------------
    float* dst = out_topk + (size_t)row * KOUT;
    dst[tid]       = key2f(x0);
    dst[tid + 256] = key2f(x1);
}

extern "C" void kernel_launch(void* const* d_in, const int* in_sizes, int n_in,
                              void* d_out, int out_size, void* d_ws, size_t ws_size,
                              hipStream_t stream) {
    const float* Q      = (const float*)d_in[0];
    const float* scores = (const float*)d_in[1];
    const float* W      = (const float*)d_in[2];
    const float* b      = (const float*)d_in[3];
    float* out_topk = (float*)d_out;                        // [16384, 512]
    float* out_k    = (float*)d_out + (size_t)NROWS * KOUT; // [16384]

    fused_kernel<<<NROWS, 256, 0, stream>>>(scores, Q, W, b, out_topk, out_k);
}

// Round 3
// 540.509 us; speedup vs baseline: 1.1584x; 1.0156x over previous
//
#include <hip/hip_runtime.h>

// Problem constants (B=4, S=4096, D=1024, BASE_K=256, MAX_K=512)
#define SDIM 4096
#define DDIM 1024
#define NROWS 16384
#define KOUT 512

__device__ __forceinline__ unsigned f2key(float f) {
    unsigned u = __float_as_uint(f);
    // monotonic bijection: larger key <=> larger float
    return (u & 0x80000000u) ? ~u : (u | 0x80000000u);
}
__device__ __forceinline__ float key2f(unsigned k) {
    unsigned u = (k & 0x80000000u) ? (k ^ 0x80000000u) : ~k;
    return __uint_as_float(u);
}
// popcount of mask restricted to lanes below mine
__device__ __forceinline__ unsigned lt_popc(unsigned long long m) {
    return __builtin_amdgcn_mbcnt_hi((unsigned)(m >> 32),
           __builtin_amdgcn_mbcnt_lo((unsigned)(m & 0xFFFFFFFFull), 0u));
}

// One WAVE per row (4 rows per 256-thread block).
//  - gate: k = trunc(256 + 256*sigmoid(Q_row . W + b))
//  - top-512 of scores_row sorted descending, exact bit-copies.
// Search: 32-bit bitwise binary search with ballot+scalar-popcount counting
// (no shuffles, no barriers). Compaction: ballot-rank (no atomics).
// Sort: bitonic-512, 8 elems/lane (e = 8*lane + r): j<8 in registers,
// j>=8 via shfl_xor. LDS only for the compaction round-trip (wave-private).
__global__ __launch_bounds__(256) void fused_kernel(
    const float* __restrict__ scores, const float* __restrict__ Q,
    const float* __restrict__ W, const float* __restrict__ bias,
    float* __restrict__ out_topk, float* __restrict__ out_k) {

    __shared__ unsigned sel[4][KOUT];   // 8 KB, one 512-slot region per wave

    const int tid  = threadIdx.x;
    const int lane = tid & 63;
    const int wid  = tid >> 6;
    const int row  = blockIdx.x * 4 + wid;

    // ---------------- gate ----------------
    {
        const float4* q4 = (const float4*)(Q + (size_t)row * DDIM);
        const float4* w4 = (const float4*)W;
        float g = 0.f;
#pragma unroll
        for (int i = 0; i < 4; ++i) {
            float4 a = q4[lane + 64 * i];
            float4 b = w4[lane + 64 * i];
            g += a.x * b.x + a.y * b.y + a.z * b.z + a.w * b.w;
        }
#pragma unroll
        for (int off = 32; off; off >>= 1) g += __shfl_down(g, off, 64);
        if (lane == 0) {
            float x   = g + bias[0];
            float imp = 1.0f / (1.0f + expf(-x));
            out_k[row] = (float)(int)(256.0f + 256.0f * imp);
        }
    }

    // ---------------- load 64 keys/lane ----------------
    unsigned key[64];
    {
        const float4* src = (const float4*)(scores + (size_t)row * SDIM);
#pragma unroll
        for (int i = 0; i < 16; ++i) {
            float4 v = src[lane + 64 * i];
            key[4 * i + 0] = f2key(v.x);
            key[4 * i + 1] = f2key(v.y);
            key[4 * i + 2] = f2key(v.z);
            key[4 * i + 3] = f2key(v.w);
        }
    }

    // ---------------- exact 512th-largest key: 32-step bitwise search -------
    // invariant: count(key >= prefix) >= 512; result prefix == 512th largest
    unsigned prefix = 0;
#pragma unroll 1
    for (int b = 31; b >= 0; --b) {
        const unsigned cand = prefix | (1u << b);
        unsigned total = 0;
#pragma unroll
        for (int i = 0; i < 64; ++i)
            total += (unsigned)__popcll(__ballot(key[i] >= cand));
        if (total >= (unsigned)KOUT) prefix = cand;
    }
    const unsigned T = prefix;

    // ---------------- compact key > T via ballot ranks (no atomics) ---------
    unsigned mtot = 0;  // uniform across wave
#pragma unroll
    for (int i = 0; i < 64; ++i) {
        bool p = key[i] > T;
        unsigned long long m = __ballot(p);
        if (p) sel[wid][mtot + lt_popc(m)] = key[i];
        mtot += (unsigned)__popcll(m);   // mtot <= 511 by definition of T
    }

    __syncthreads();  // belt&braces: order wave's LDS writes before reads

    // ---------------- read back 8/lane, pad ties with T ---------------------
    unsigned x[8];
#pragma unroll
    for (int r = 0; r < 8; ++r) {
        unsigned idx = 8 * (unsigned)lane + r;
        unsigned v = sel[wid][idx];          // garbage beyond mtot, masked next
        x[r] = (idx < mtot) ? v : T;
    }

    // ---------------- bitonic sort 512 descending, wave-private -------------
    // element index e = 8*lane + r; pair dir: descending iff (e & kk) == 0;
    // elem keeps max iff ((e&kk)==0) == ((e&j)==0)
#pragma unroll
    for (int kk = 2; kk <= 512; kk <<= 1) {
        // cross-lane stages: j = kk/2 .. 8  (lane xor mask = j/8)
#pragma unroll
        for (int j = kk >> 1; j >= 8; j >>= 1) {
            bool km = ((((8 * lane) & kk) == 0) == (((8 * lane) & j) == 0));
#pragma unroll
            for (int r = 0; r < 8; ++r) {
                unsigned p  = __shfl_xor(x[r], j >> 3, 64);
                unsigned mx = x[r] > p ? x[r] : p;
                unsigned mn = x[r] > p ? p : x[r];
                x[r] = km ? mx : mn;
            }
        }
        // in-register stages: j = min(kk/2,4) .. 1
#pragma unroll
        for (int j = (kk >> 1) < 4 ? (kk >> 1) : 4; j >= 1; j >>= 1) {
#pragma unroll
            for (int r = 0; r < 8; ++r) {
                if ((r & j) == 0) {
                    int rp = r | j;
                    unsigned a = x[r], b = x[rp];
                    bool d = (((8 * lane + r) & kk) == 0);
                    unsigned hi = a > b ? a : b;
                    unsigned lo = a > b ? b : a;
                    x[r]  = d ? hi : lo;
                    x[rp] = d ? lo : hi;
                }
            }
        }
    }

    // ---------------- store: 8 consecutive floats per lane ------------------
    float4* dst = (float4*)(out_topk + (size_t)row * KOUT);
    dst[2 * lane + 0] = make_float4(key2f(x[0]), key2f(x[1]), key2f(x[2]), key2f(x[3]));
    dst[2 * lane + 1] = make_float4(key2f(x[4]), key2f(x[5]), key2f(x[6]), key2f(x[7]));
}

extern "C" void kernel_launch(void* const* d_in, const int* in_sizes, int n_in,
                              void* d_out, int out_size, void* d_ws, size_t ws_size,
                              hipStream_t stream) {
    const float* Q      = (const float*)d_in[0];
    const float* scores = (const float*)d_in[1];
    const float* W      = (const float*)d_in[2];
    const float* b      = (const float*)d_in[3];
    float* out_topk = (float*)d_out;                        // [16384, 512]
    float* out_k    = (float*)d_out + (size_t)NROWS * KOUT; // [16384]

    fused_kernel<<<NROWS / 4, 256, 0, stream>>>(scores, Q, W, b, out_topk, out_k);
}

// Round 4
// 502.450 us; speedup vs baseline: 1.2462x; 1.0757x over previous
//
#include <hip/hip_runtime.h>

// Problem constants (B=4, S=4096, D=1024, BASE_K=256, MAX_K=512)
#define SDIM 4096
#define DDIM 1024
#define NROWS 16384
#define KOUT 512

__device__ __forceinline__ unsigned f2key(float f) {
    unsigned u = __float_as_uint(f);
    // monotonic bijection: larger key <=> larger float
    return (u & 0x80000000u) ? ~u : (u | 0x80000000u);
}
__device__ __forceinline__ float key2f(unsigned k) {
    unsigned u = (k & 0x80000000u) ? (k ^ 0x80000000u) : ~k;
    return __uint_as_float(u);
}
// popcount of mask restricted to lanes below mine
__device__ __forceinline__ unsigned lt_popc(unsigned long long m) {
    return __builtin_amdgcn_mbcnt_hi((unsigned)(m >> 32),
           __builtin_amdgcn_mbcnt_lo((unsigned)(m & 0xFFFFFFFFull), 0u));
}

// One WAVE per row (4 rows per 256-thread block).
// __launch_bounds__(256, 1): VGPR cap 512 so key[64] stays RESIDENT in
// registers (R3's default cap of 80 spilled it to scratch -> latency-bound).
__global__ __launch_bounds__(256, 1) void fused_kernel(
    const float* __restrict__ scores, const float* __restrict__ Q,
    const float* __restrict__ W, const float* __restrict__ bias,
    float* __restrict__ out_topk, float* __restrict__ out_k) {

    __shared__ unsigned sel[4][KOUT];   // 8 KB, one 512-slot region per wave

    const int tid  = threadIdx.x;
    const int lane = tid & 63;
    const int wid  = tid >> 6;
    const int row  = blockIdx.x * 4 + wid;

    // ---------------- gate ----------------
    {
        const float4* q4 = (const float4*)(Q + (size_t)row * DDIM);
        const float4* w4 = (const float4*)W;
        float g = 0.f;
#pragma unroll
        for (int i = 0; i < 4; ++i) {
            float4 a = q4[lane + 64 * i];
            float4 b = w4[lane + 64 * i];
            g += a.x * b.x + a.y * b.y + a.z * b.z + a.w * b.w;
        }
#pragma unroll
        for (int off = 32; off; off >>= 1) g += __shfl_down(g, off, 64);
        if (lane == 0) {
            float x   = g + bias[0];
            float imp = 1.0f / (1.0f + expf(-x));
            out_k[row] = (float)(int)(256.0f + 256.0f * imp);
        }
    }

    // ---------------- load 64 keys/lane into registers ----------------
    unsigned key[64];
    {
        const float4* src = (const float4*)(scores + (size_t)row * SDIM);
#pragma unroll
        for (int i = 0; i < 16; ++i) {
            float4 v = src[lane + 64 * i];
            key[4 * i + 0] = f2key(v.x);
            key[4 * i + 1] = f2key(v.y);
            key[4 * i + 2] = f2key(v.z);
            key[4 * i + 3] = f2key(v.w);
        }
    }

    // ---------------- threshold: bitwise binary search w/ early exit --------
    // invariant: count(key >= prefix) >= 512 at all times.
    // exit early when count(key >= prefix) == 512 exactly; then
    // T = min{key : key >= prefix} is the exact 512th-largest key.
    // (If the loop runs all 32 bits, that min equals prefix itself.)
    unsigned prefix = 0;
#pragma unroll 1
    for (int b = 31; b >= 0; --b) {
        const unsigned cand = prefix | (1u << b);
        unsigned total = 0;
#pragma unroll
        for (int i = 0; i < 64; ++i)
            total += (unsigned)__popcll(__ballot(key[i] >= cand));
        if (total >= (unsigned)KOUT) {
            prefix = cand;
            if (total == (unsigned)KOUT) break;   // wave-uniform branch
        }
    }
    unsigned tmin = 0xFFFFFFFFu;
#pragma unroll
    for (int i = 0; i < 64; ++i) {
        unsigned t = (key[i] >= prefix) ? key[i] : 0xFFFFFFFFu;
        tmin = t < tmin ? t : tmin;
    }
#pragma unroll
    for (int off = 32; off; off >>= 1) {
        unsigned o = __shfl_xor(tmin, off, 64);
        tmin = o < tmin ? o : tmin;
    }
    const unsigned T = tmin;   // exact 512th-largest key

    // ---------------- compact key > T via ballot ranks (no atomics) ---------
    unsigned mtot = 0;  // uniform across wave
#pragma unroll
    for (int i = 0; i < 64; ++i) {
        bool p = key[i] > T;
        unsigned long long m = __ballot(p);
        if (p) sel[wid][mtot + lt_popc(m)] = key[i];
        mtot += (unsigned)__popcll(m);   // mtot <= 511 by definition of T
    }

    __syncthreads();  // order this wave's LDS writes before readback

    // ---------------- read back 8/lane, pad ties with T ---------------------
    unsigned x[8];
#pragma unroll
    for (int r = 0; r < 8; ++r) {
        unsigned idx = 8 * (unsigned)lane + r;
        unsigned v = sel[wid][idx];
        x[r] = (idx < mtot) ? v : T;
    }

    // ---------------- bitonic sort 512 descending, wave-private -------------
    // element index e = 8*lane + r; elem keeps max iff ((e&kk)==0)==((e&j)==0)
#pragma unroll
    for (int kk = 2; kk <= 512; kk <<= 1) {
        // cross-lane stages: j = kk/2 .. 8  (lane xor mask = j/8)
#pragma unroll
        for (int j = kk >> 1; j >= 8; j >>= 1) {
            bool km = ((((8 * lane) & kk) == 0) == (((8 * lane) & j) == 0));
#pragma unroll
            for (int r = 0; r < 8; ++r) {
                unsigned p  = __shfl_xor(x[r], j >> 3, 64);
                unsigned mx = x[r] > p ? x[r] : p;
                unsigned mn = x[r] > p ? p : x[r];
                x[r] = km ? mx : mn;
            }
        }
        // in-register stages: j = min(kk/2,4) .. 1
#pragma unroll
        for (int j = (kk >> 1) < 4 ? (kk >> 1) : 4; j >= 1; j >>= 1) {
#pragma unroll
            for (int r = 0; r < 8; ++r) {
                if ((r & j) == 0) {
                    int rp = r | j;
                    unsigned a = x[r], b = x[rp];
                    bool d = (((8 * lane + r) & kk) == 0);
                    unsigned hi = a > b ? a : b;
                    unsigned lo = a > b ? b : a;
                    x[r]  = d ? hi : lo;
                    x[rp] = d ? lo : hi;
                }
            }
        }
    }

    // ---------------- store: 8 consecutive floats per lane ------------------
    float4* dst = (float4*)(out_topk + (size_t)row * KOUT);
    dst[2 * lane + 0] = make_float4(key2f(x[0]), key2f(x[1]), key2f(x[2]), key2f(x[3]));
    dst[2 * lane + 1] = make_float4(key2f(x[4]), key2f(x[5]), key2f(x[6]), key2f(x[7]));
}

extern "C" void kernel_launch(void* const* d_in, const int* in_sizes, int n_in,
                              void* d_out, int out_size, void* d_ws, size_t ws_size,
                              hipStream_t stream) {
    const float* Q      = (const float*)d_in[0];
    const float* scores = (const float*)d_in[1];
    const float* W      = (const float*)d_in[2];
    const float* b      = (const float*)d_in[3];
    float* out_topk = (float*)d_out;                        // [16384, 512]
    float* out_k    = (float*)d_out + (size_t)NROWS * KOUT; // [16384]

    fused_kernel<<<NROWS / 4, 256, 0, stream>>>(scores, Q, W, b, out_topk, out_k);
}